// Round 13
// baseline (58.021 us; speedup 1.0000x reference)
//
#include <hip/hip_runtime.h>

typedef __attribute__((ext_vector_type(8))) short short8;
typedef __attribute__((ext_vector_type(4))) float f32x4;

#define CI    128
#define CO_   256
#define HW_   56
#define PLANE 3136
#define NB    16
#define STOT  50176
#define KTOT  1152
#define OUTN  802816   // CO_*PLANE
#define PLSZ  3211264ull   // one cb-plane of Xt2: 50176 rows x 64 B

// ws layout: [0, 12845056) Xt2 bf16, 4 planes [cb][S][64B] ; [12845056, +589824) Wpre ; 256B zeros
#define XT_BYTES   12845056ull
#define WP_USHORTS 294912
#define WS_NEED    (12845056ull + 589824ull + 256ull)

__device__ __forceinline__ unsigned short f2bf(float f) {
  unsigned u = __float_as_uint(f);
  u += 0x7FFFu + ((u >> 16) & 1u);   // RNE
  return (unsigned short)(u >> 16);
}

__device__ __forceinline__ void gload16(void* lds, const void* g) {
  __builtin_amdgcn_global_load_lds(
      (const __attribute__((address_space(1))) unsigned int*)g,
      (__attribute__((address_space(3))) unsigned int*)lds, 16, 0, 0);
}

template <int N> __device__ __forceinline__ void vmwait() {
  asm volatile("s_waitcnt vmcnt(%0)" ::"n"(N) : "memory");
}

// ---------------- fused prep: blocks 0..1599 = prep_x ; 1600..1743 = prep_w ----------------
__global__ __launch_bounds__(256) void prep_fused(const float* __restrict__ X,
                                                  const float* __restrict__ W,
                                                  unsigned short* __restrict__ Xt,
                                                  unsigned short* __restrict__ Wp) {
  const int t = threadIdx.x;
  if (blockIdx.x < 1600) {
    // ---- prep_x: NCHW fp32 -> Xt2[cb][S][64B] bf16 (4 contiguous planes) [verified R12]
    __shared__ __align__(16) unsigned short tile[32][132];
    const int bx = blockIdx.x;
    const int n   = bx / 100;
    const int rem = bx % 100;
    const int cib = rem / 25;          // == cb plane
    const int spb = rem % 25;
    const int sp0 = spb * 128;
    const float* src = X + (size_t)(n * CI + cib * 32) * PLANE;
#pragma unroll
    for (int j = 0; j < 4; ++j) {
      int f = t + 256 * j;
      int ci  = f >> 5;
      int sp4 = (f & 31) * 4;
      if (sp0 + sp4 < PLANE) {
        f32x4 v = *(const f32x4*)(src + (size_t)ci * PLANE + sp0 + sp4);
#pragma unroll
        for (int e = 0; e < 4; ++e) tile[ci][sp4 + e] = f2bf(v[e]);
      }
    }
    __syncthreads();
    unsigned short* dstp = Xt + (size_t)cib * (PLSZ / 2) + ((size_t)n * PLANE + sp0) * 32;
#pragma unroll
    for (int j = 0; j < 2; ++j) {
      int g = t + 256 * j;
      int sp = g >> 2;
      int q  = g & 3;
      if (sp0 + sp < PLANE) {
        short8 v;
#pragma unroll
        for (int e = 0; e < 8; ++e) v[e] = (short)tile[q * 8 + e][sp];
        *(short8*)(dstp + (size_t)sp * 32 + q * 8) = v;
      }
    }
  } else {
    // ---- prep_w: OIHW fp32 -> Wpre2, DIRECT-A layout (A skips LDS):
    // chunk u (16B): sub-tile sub=u>>9 = ((r*4+cb)*2+mt); c=u&511 = wm*256 + m*64 + lane.
    // Holds W[co = mt*128+wm*64+m*16+(lane&15)][ci = cb*32+(lane>>4)*8+e][r]
    // -> wave (wm) frag read a[m] = coalesced 1KB global load, operand map identical to
    //    the verified LDS path (lane&15 = row-in-16, lane>>4 = k-granule).
    const int u = (blockIdx.x - 1600) * 256 + t;   // 0..36863
    const int sub = u >> 9;
    const int c   = u & 511;
    const int mt  = sub & 1;
    const int cb  = (sub >> 1) & 3;
    const int r   = sub >> 3;
    const int wmh = c >> 8;
    const int m   = (c >> 6) & 3;
    const int ln  = c & 63;
    const int co  = mt * 128 + wmh * 64 + m * 16 + (ln & 15);
    const int ci0 = cb * 32 + (ln >> 4) * 8;
    short8 v;
#pragma unroll
    for (int e = 0; e < 8; ++e)
      v[e] = (short)f2bf(W[(size_t)co * KTOT + (size_t)(ci0 + e) * 9 + r]);
    *(short8*)(Wp + (size_t)u * 8) = v;
    if (u < 16) {
      short8 z = {0, 0, 0, 0, 0, 0, 0, 0};
      *(short8*)(Wp + WP_USHORTS + u * 8) = z;
    }
  }
}

// ---------------- conv_gemm: 128x128, 4 waves, B-only LDS ring-3, A direct L2->regs ----------
// LDS traffic/step halved (48KB -> 24KB: B 16KB read + 8KB write); A = 4 coalesced
// global dwordx4 into a3[3][4] reg ring (triple-buffered, landing 2 steps ahead).
// vmcnt ledger: 6 ops/body (2 B-stage + 4 A-pref) -> steady vmwait<6>, tail 4/0.
__global__ __launch_bounds__(256, 3) void conv_gemm(const unsigned short* __restrict__ Xt,
                                                    const unsigned short* __restrict__ Wp,
                                                    const float* __restrict__ bias,
                                                    float* __restrict__ out) {
  __shared__ __align__(1024) char smem[24576];  // ring of 3 x B 8KB
  const int t    = threadIdx.x;
  const int lane = t & 63;
  const int wid  = t >> 6;
  const int wm   = wid >> 1, wn = wid & 1;

  int bx = blockIdx.x;
  bx = (bx & 7) * 98 + (bx >> 3);     // XCD swizzle, bijective (784 = 8*98)
  const int mt  = bx & 1;
  const int spt = bx >> 1;            // 0..391

  // --- B staging (verified R12): wave stages rows wid*32..+31; lane -> row +(lane>>2),
  //     source granule pre-swizzled kgB so linear LDS dest + swizzled frag read agree.
  const int kgB = (lane & 3) ^ ((lane >> 3) & 3);
  const int S0 = spt * 128 + wid * 32 + (lane >> 2);
  const int S1 = S0 + 16;
  const int hw0 = S0 % PLANE, h0 = hw0 / HW_, w0 = hw0 - h0 * HW_;
  const int hw1 = S1 % PLANE, h1 = hw1 / HW_, w1 = hw1 - h1 * HW_;
  int vm0 = 0, vm1 = 0;
#pragma unroll
  for (int r = 0; r < 9; ++r) {
    int dh = r / 3 - 1, dw = r % 3 - 1;
    vm0 |= (int)(((unsigned)(h0 + dh) < HW_) & ((unsigned)(w0 + dw) < HW_)) << r;
    vm1 |= (int)(((unsigned)(h1 + dh) < HW_) & ((unsigned)(w1 + dw) < HW_)) << r;
  }
  const char* xb0 = (const char*)Xt + (size_t)S0 * 64 + kgB * 16;
  const char* xb1 = (const char*)Xt + (size_t)S1 * 64 + kgB * 16;
  const char* zb  = (const char*)(Wp + WP_USHORTS) + (lane & 3) * 16;
  // A direct-read base: sub-tile s at s*16384 + mt*8192; within: wm*4096 + m*1024 + lane*16
  const char* wpAL = (const char*)Wp + mt * 8192 + wm * 4096 + lane * 16;

  // B fragment read offsets (64B rows, granule swizzle, lane-constant) [verified]
  const int swz  = ((lane >> 4) ^ ((lane >> 1) & 3)) * 16;
  const int boff = (wn * 64 + (lane & 15)) * 64 + swz;   // + n*1024

  f32x4 acc[4][4];
  const f32x4 zf = {0.f, 0.f, 0.f, 0.f};
#pragma unroll
  for (int m = 0; m < 4; ++m)
#pragma unroll
    for (int n = 0; n < 4; ++n) acc[m][n] = zf;

  short8 a3[3][4];   // A reg ring: a3[s%3] holds frags of sub-tile s (static-indexed)

  auto STAGE_B = [&](int s1) {
    char* buf = smem + (s1 % 3) * 8192;
    const int r = s1 >> 2, cb = s1 & 3;
    const int dh = r / 3 - 1, dw = r % 3 - 1;
    const long ro = (long)(dh * HW_ + dw) * 64 + (long)cb * PLSZ;
    const bool v0 = (vm0 >> r) & 1;
    const bool v1 = (vm1 >> r) & 1;
    gload16(buf + wid * 2048,        v0 ? xb0 + ro : zb);
    gload16(buf + wid * 2048 + 1024, v1 ? xb1 + ro : zb);
  };
#define A_PREF(S1)                                                                \
  {                                                                               \
    const char* ab_ = wpAL + (size_t)(S1) * 16384;                                \
    _Pragma("unroll") for (int m = 0; m < 4; ++m)                                 \
      a3[(S1) % 3][m] = *(const short8*)(ab_ + m * 1024);                         \
  }

  // prologue: B(0),B(1) ; A(0) ; B(2) ; A(1)  -> queue matches steady vmwait<6>
  STAGE_B(0); STAGE_B(1);
  A_PREF(0)
  STAGE_B(2);
  A_PREF(1)

#pragma unroll
  for (int s = 0; s < 36; ++s) {
    // certify B(s) [done one step earlier] and A(s); leave B(s+2)+A(s+1) (6 ops) in flight
    if (s <= 33)      vmwait<6>();
    else if (s == 34) vmwait<4>();
    else              vmwait<0>();
    __builtin_amdgcn_s_barrier();      // cross-wave: B(s) LDS visible to all

    const char* rb = smem + (s % 3) * 8192;
    short8 b[4];
#pragma unroll
    for (int n = 0; n < 4; ++n) b[n] = *(const short8*)(rb + boff + n * 1024);

    __builtin_amdgcn_s_setprio(1);
#pragma unroll
    for (int m = 0; m < 4; ++m)
#pragma unroll
      for (int n = 0; n < 4; ++n)
        acc[m][n] = __builtin_amdgcn_mfma_f32_16x16x32_bf16(a3[s % 3][m], b[n], acc[m][n], 0, 0, 0);
    __builtin_amdgcn_s_setprio(0);

    if (s < 33) {
      __builtin_amdgcn_s_barrier();    // all waves done reading buf[s%3] (WAR)
      STAGE_B(s + 3);                  // 2 VMEM
    }
    if (s <= 33) A_PREF(s + 2)         // 4 VMEM into a3[(s+2)%3] (free: last used at s-1)
  }

  // ---- epilogue: D row = co = (lane>>4)*4+reg, col = sp = lane&15
#pragma unroll
  for (int nf = 0; nf < 4; ++nf) {
    int S = spt * 128 + wn * 64 + nf * 16 + (lane & 15);
    int nimg = S / PLANE, hw = S - nimg * PLANE;
    float* ob = out + (size_t)nimg * OUTN + hw;
#pragma unroll
    for (int mf = 0; mf < 4; ++mf) {
      int cob = mt * 128 + wm * 64 + mf * 16 + (lane >> 4) * 4;
#pragma unroll
      for (int r2 = 0; r2 < 4; ++r2)
        ob[(size_t)(cob + r2) * PLANE] = acc[mf][nf][r2] + bias[cob + r2];
    }
  }
}

// ---------------- fallback: naive direct conv (only if ws too small) ----------------
__global__ __launch_bounds__(256) void conv_naive(const float* __restrict__ X,
                                                  const float* __restrict__ W,
                                                  const float* __restrict__ bias,
                                                  float* __restrict__ out) {
  int idx = blockIdx.x * 256 + threadIdx.x;
  int hw = idx % PLANE;
  int co = (idx / PLANE) & 255;
  int n  = idx / (PLANE * 256);
  int h = hw / HW_, w = hw - h * HW_;
  float acc = bias[co];
  const float* xp = X + (size_t)n * CI * PLANE;
  const float* wp = W + (size_t)co * KTOT;
  for (int ci = 0; ci < CI; ++ci) {
#pragma unroll
    for (int kh = 0; kh < 3; ++kh) {
      int y = h + kh - 1;
      if ((unsigned)y >= HW_) continue;
#pragma unroll
      for (int kw = 0; kw < 3; ++kw) {
        int x = w + kw - 1;
        if ((unsigned)x >= HW_) continue;
        acc += xp[(size_t)ci * PLANE + y * HW_ + x] * wp[ci * 9 + kh * 3 + kw];
      }
    }
  }
  out[idx] = acc;
}

extern "C" void kernel_launch(void* const* d_in, const int* in_sizes, int n_in,
                              void* d_out, int out_size, void* d_ws, size_t ws_size,
                              hipStream_t stream) {
  (void)in_sizes; (void)n_in; (void)out_size;
  const float* X = (const float*)d_in[0];
  const float* W = (const float*)d_in[1];
  const float* b = (const float*)d_in[2];
  float* out = (float*)d_out;
  if (ws_size >= WS_NEED) {
    unsigned short* Xt = (unsigned short*)d_ws;
    unsigned short* Wp = (unsigned short*)((char*)d_ws + XT_BYTES);
    prep_fused<<<1744, 256, 0, stream>>>(X, W, Xt, Wp);
    conv_gemm<<<784, 256, 0, stream>>>(Xt, Wp, b, out);
  } else {
    conv_naive<<<(NB * CO_ * PLANE + 255) / 256, 256, 0, stream>>>(X, W, b, out);
  }
}